// Round 2
// baseline (1795.271 us; speedup 1.0000x reference)
//
#include <hip/hip_runtime.h>
#include <hip/hip_cooperative_groups.h>
#include <math.h>

namespace cg = cooperative_groups;

#define NN 4096
#define NE 16384
#define NG 64
#define NBLK 512
#define GSZ (NBLK * 256)

// ---- ws layout (float offsets) ----
#define OFF_DEG   0         // 4096
#define OFF_H1    4096      // 4096*32
#define OFF_H2    135168    // 4096*64
#define OFF_H3    397312    // 4096*128
#define OFF_ST1   921600    // 64
#define OFF_ST2   921664    // 128
#define OFF_ST3   921792    // 256
#define OFF_POOL  922048    // 64*128
#define OFF_WC1   930240    // 16*288  = 4608
#define OFF_WC2   934848    // 32*576  = 18432
#define OFF_WC3   953280    // 64*1152 = 73728
#define OFF_Y     1027008   // 4096*1152 (reused across layers)
#define ZERO_FLOATS 930240  // zero deg/h/stats/pool only

struct Params {
    const float *x, *eattr;
    const int *ei, *batch;
    const float *We1, *be1, *bias1, *Wr1, *br1, *bg1, *bb1, *a1;
    const float *We2, *be2, *bias2, *Wr2, *br2, *bg2, *bb2, *a2;
    const float *We3, *be3, *bias3, *Wr3, *br3, *bg3, *bb3, *a3;
    const float *Wi, *bi, *Wj, *bj, *Wfc, *bfc;
    float *ws, *out;
};

// Wcat[i*(9*COUT) + f*COUT + o] = f<8 ? We[f*CIN*COUT + o*CIN + i] : be[o*CIN + i]
__device__ __forceinline__ void tr_wcat(const float* We, const float* be,
                                        float* Wcat, int CIN, int COUT, int t) {
    int nine = 9 * COUT;
    int i = t / nine; int r = t - i * nine;
    int f = r / COUT; int o = r - f * COUT;
    Wcat[t] = (f < 8) ? We[f * CIN * COUT + o * CIN + i] : be[o * CIN + i];
}

// ---------------- phase 0: zero deg/h/st/pool ----------------
__device__ __forceinline__ void ph_zero(float* ws, int gtid) {
    float4 z = make_float4(0.f, 0.f, 0.f, 0.f);
    float4* w4 = (float4*)ws;
    for (int i = gtid; i < ZERO_FLOATS / 4; i += GSZ) w4[i] = z;
}

// ---------------- phase 1: Wcat build + degree ----------------
__device__ __forceinline__ void ph_prep(const Params& p, int gtid) {
    float* ws = p.ws;
    for (int t0 = gtid; t0 < 113152; t0 += GSZ) {
        int t = t0;
        if (t < 4608)  { tr_wcat(p.We1, p.be1, ws + OFF_WC1, 16, 32, t); continue; }
        t -= 4608;
        if (t < 18432) { tr_wcat(p.We2, p.be2, ws + OFF_WC2, 32, 64, t); continue; }
        t -= 18432;
        if (t < 73728) { tr_wcat(p.We3, p.be3, ws + OFF_WC3, 64, 128, t); continue; }
        t -= 73728;
        atomicAdd(&ws[OFF_DEG + p.ei[t]], 1.0f);
    }
}

// ---------------- proj: Y[n,col] = norm[n] * sum_i bnp(A[n,i]) * B[i,col] ----------------
template<int K, bool BN>
__device__ void ph_proj(const float* __restrict__ A, const float* __restrict__ Bm,
                        const float* __restrict__ deg, float* __restrict__ Y,
                        int Ncols, int nyb,
                        const float* st, const float* g, const float* b, const float* a,
                        float* smem, int bid, int tid)
{
    float* sA = smem;                 // K*68
    float* sB = smem + K * 68;        // K*68
    float* sS = smem + 2 * K * 68;    // K
    float* sT = sS + K;               // K
    if (BN) {
        if (tid < K) {
            float mean = st[tid] * (1.f / NN);
            float var  = st[K + tid] * (1.f / NN) - mean * mean;
            var = fmaxf(var, 0.f);
            float s = rsqrtf(var + 1e-5f) * g[tid];
            sS[tid] = s;
            sT[tid] = b[tid] - mean * s;
        }
    }
    float al = BN ? a[0] : 0.f;
    const int ntiles = 64 * nyb;
    for (int tile = bid; tile < ntiles; tile += NBLK) {
        const int m0 = (tile & 63) * 64;
        const int n0 = (tile >> 6) * 64;
        __syncthreads();   // smem WAR guard (+orders sS/sT on first tile)
        for (int t = tid; t < 64 * K; t += 256) {
            int m = t / K, i = t - m * K;
            float v = A[(m0 + m) * K + i];
            if (BN) { v = fmaf(v, sS[i], sT[i]); v = v >= 0.f ? v : al * v; }
            sA[i * 68 + m] = v;
        }
        for (int t = tid; t < 64 * K; t += 256) {
            int i = t >> 6, n = t & 63;
            int col = n0 + n;
            sB[i * 68 + n] = (col < Ncols) ? Bm[i * Ncols + col] : 0.f;
        }
        __syncthreads();
        const int tn = tid & 15, tm = tid >> 4;
        float acc[4][4] = {{0.f}};
#pragma unroll 8
        for (int i = 0; i < K; ++i) {
            float4 av = *(const float4*)&sA[i * 68 + tm * 4];
            float4 bv = *(const float4*)&sB[i * 68 + tn * 4];
            acc[0][0] += av.x * bv.x; acc[0][1] += av.x * bv.y; acc[0][2] += av.x * bv.z; acc[0][3] += av.x * bv.w;
            acc[1][0] += av.y * bv.x; acc[1][1] += av.y * bv.y; acc[1][2] += av.y * bv.z; acc[1][3] += av.y * bv.w;
            acc[2][0] += av.z * bv.x; acc[2][1] += av.z * bv.y; acc[2][2] += av.z * bv.z; acc[2][3] += av.z * bv.w;
            acc[3][0] += av.w * bv.x; acc[3][1] += av.w * bv.y; acc[3][2] += av.w * bv.z; acc[3][3] += av.w * bv.w;
        }
#pragma unroll
        for (int mm = 0; mm < 4; ++mm) {
            int m = m0 + tm * 4 + mm;
            float d = deg[m];
            float nrm = d > 0.f ? 1.f / d : 0.f;
#pragma unroll
            for (int nn = 0; nn < 4; ++nn) {
                int col = n0 + tn * 4 + nn;
                if (col < Ncols) Y[(size_t)m * Ncols + col] = acc[mm][nn] * nrm;
            }
        }
    }
}

// ---------------- egather: h[dst,4q..] += sum_f ea'[e,f] * Y[src, f*COUT+4q..] ----------------
template<int COUT>
__device__ void ph_egather(const float* __restrict__ Y, const float* __restrict__ eattr,
                           const int* __restrict__ ei, float* __restrict__ h, int gtid)
{
    constexpr int TPE = COUT / 4;
    for (int idx = gtid; idx < NE * TPE; idx += GSZ) {
        int e = idx / TPE;
        int q = idx - e * TPE;
        int src = ei[e], dst = ei[NE + e];
        const float4* y4 = (const float4*)(Y + (size_t)src * (9 * COUT));
        const float4* ea4 = (const float4*)(eattr + e * 8);
        float4 ea0 = ea4[0], ea1 = ea4[1];
        float4 acc = y4[8 * TPE + q];     // be-term, ea' = 1
#define FMA4(s, v) { float4 _t = (v); acc.x += (s)*_t.x; acc.y += (s)*_t.y; acc.z += (s)*_t.z; acc.w += (s)*_t.w; }
        FMA4(ea0.x, y4[0 * TPE + q]);
        FMA4(ea0.y, y4[1 * TPE + q]);
        FMA4(ea0.z, y4[2 * TPE + q]);
        FMA4(ea0.w, y4[3 * TPE + q]);
        FMA4(ea1.x, y4[4 * TPE + q]);
        FMA4(ea1.y, y4[5 * TPE + q]);
        FMA4(ea1.z, y4[6 * TPE + q]);
        FMA4(ea1.w, y4[7 * TPE + q]);
#undef FMA4
        float* hp = h + (size_t)dst * COUT + 4 * q;
        atomicAdd(hp + 0, acc.x);
        atomicAdd(hp + 1, acc.y);
        atomicAdd(hp + 2, acc.z);
        atomicAdd(hp + 3, acc.w);
    }
}

// ---------------- node: residual + bias, accumulate BN stats (NB=8, 512 tiles) ----------------
template<int CIN, int COUT, bool BN>
__device__ void ph_node(const float* __restrict__ xin, const float* __restrict__ Wr,
                        const float* __restrict__ br, const float* __restrict__ bias,
                        float* __restrict__ h, float* __restrict__ st_out,
                        const float* st_in, const float* g, const float* b, const float* a,
                        float* smem, int bid, int tid)
{
    constexpr int NL = 256 / COUT;
    constexpr int NB = 8;
    constexpr int KN = NB / NL;
    constexpr int CINP = CIN | 1;
    float* sWr  = smem;                     // CIN*COUT
    float* sX   = smem + CIN * COUT;        // NB*CINP
    float* sred = sX + NB * CINP;           // 256
    float* sS   = sred + 256;               // CIN
    float* sT   = sS + CIN;                 // CIN
    const int nbase = bid * NB;             // 512*8 = 4096

    if (BN) {
        if (tid < CIN) {
            float mean = st_in[tid] * (1.f / NN);
            float var  = st_in[CIN + tid] * (1.f / NN) - mean * mean;
            var = fmaxf(var, 0.f);
            float s = rsqrtf(var + 1e-5f) * g[tid];
            sS[tid] = s;
            sT[tid] = b[tid] - mean * s;
        }
    }
    for (int t = tid; t < CIN * COUT; t += 256) sWr[t] = Wr[t];
    __syncthreads();
    float al = BN ? a[0] : 0.f;

    for (int t = tid; t < NB * CIN; t += 256) {
        int r = t / CIN, i = t - r * CIN;
        float v = xin[(nbase + r) * CIN + i];
        if (BN) { v = fmaf(v, sS[i], sT[i]); v = v >= 0.f ? v : al * v; }
        sX[r * CINP + i] = v;
    }
    __syncthreads();

    const int o = tid % COUT;
    const int nl = tid / COUT;
    const float addc = bias[o] + br[o];
    float sum = 0.f, sumsq = 0.f;
#pragma unroll
    for (int k = 0; k < KN; ++k) {
        int r = nl * KN + k;
        float acc = addc;
        for (int i = 0; i < CIN; ++i)
            acc += sX[r * CINP + i] * sWr[i * COUT + o];
        int gi = (nbase + r) * COUT + o;
        float hv = h[gi] + acc;
        h[gi] = hv;
        sum += hv; sumsq += hv * hv;
    }
    sred[tid] = sum;
    __syncthreads();
    if (tid < COUT) {
        float s = 0.f;
        for (int q = 0; q < NL; ++q) s += sred[q * COUT + tid];
        atomicAdd(&st_out[tid], s);
    }
    __syncthreads();
    sred[tid] = sumsq;
    __syncthreads();
    if (tid < COUT) {
        float s = 0.f;
        for (int q = 0; q < NL; ++q) s += sred[q * COUT + tid];
        atomicAdd(&st_out[COUT + tid], s);
    }
}

// ---------------- pool: BN3+PReLU3 on load, gated attention, scatter to graphs (NB=8) ----------------
__device__ void ph_pool(const float* __restrict__ h3, const int* __restrict__ batch,
                        const float* __restrict__ Wi, const float* __restrict__ bi,
                        const float* __restrict__ Wj, const float* __restrict__ bj,
                        float* __restrict__ pooled,
                        const float* st, const float* g, const float* b, const float* a,
                        float* smem, int bid, int tid)
{
    constexpr int NB = 8, KN = 4;   // NL = 2
    float* sH = smem;               // NB*128
    float* sS = smem + NB * 128;    // 128
    float* sT = sS + 128;           // 128
    int*   sBt = (int*)(sT + 128);  // NB
    const int nbase = bid * NB;

    if (tid < 128) {
        float mean = st[tid] * (1.f / NN);
        float var  = st[128 + tid] * (1.f / NN) - mean * mean;
        var = fmaxf(var, 0.f);
        float s = rsqrtf(var + 1e-5f) * g[tid];
        sS[tid] = s;
        sT[tid] = b[tid] - mean * s;
    }
    if (tid < NB) sBt[tid] = batch[nbase + tid];
    __syncthreads();
    const float al = a[0];

    for (int t = tid; t < NB * 128; t += 256) {
        int c = t & 127;
        float v = h3[nbase * 128 + t];
        v = fmaf(v, sS[c], sT[c]);
        v = v >= 0.f ? v : al * v;
        sH[t] = v;
    }
    __syncthreads();

    const int o = tid & 127, nl = tid >> 7;
    float gacc[KN], facc[KN];
#pragma unroll
    for (int k = 0; k < KN; ++k) { gacc[k] = 0.f; facc[k] = 0.f; }
    for (int i = 0; i < 128; ++i) {
        float wi = Wi[i * 128 + o], wj = Wj[i * 128 + o];
#pragma unroll
        for (int k = 0; k < KN; ++k) {
            float hv = sH[(nl * KN + k) * 128 + i];
            gacc[k] += hv * wi;
            facc[k] += hv * wj;
        }
    }
    float bio = bi[o], bjo = bj[o];
#pragma unroll
    for (int k = 0; k < KN; ++k) {
        int r = nl * KN + k;
        float gate = 1.f / (1.f + expf(-(gacc[k] + bio)));
        float feat = tanhf(facc[k] + bjo);
        atomicAdd(&pooled[sBt[r] * 128 + o], gate * feat);
    }
}

// ---------------- final: tanh(pooled) @ Wfc + bfc ----------------
__device__ void ph_final(const float* __restrict__ pooled, const float* __restrict__ Wfc,
                         const float* __restrict__ bfc, float* __restrict__ out,
                         float* smem, int bid, int tid)
{
    if (bid >= NG) return;
    float* sP = smem;
    if (tid < 128) sP[tid] = tanhf(pooled[bid * 128 + tid]);
    __syncthreads();
    float z = bfc[tid];
    for (int i = 0; i < 128; ++i) z += sP[i] * Wfc[i * 256 + tid];
    int oidx = (tid < 128) ? (bid * 128 + tid) : (NG * 128 + bid * 128 + (tid - 128));
    out[oidx] = z;
}

// ================= mega kernel (cooperative) =================
__global__ __launch_bounds__(256, 2) void mega(Params p)
{
    __shared__ float smem[9728];
    cg::grid_group gg = cg::this_grid();
    const int tid = threadIdx.x, bid = blockIdx.x;
    const int gtid = bid * 256 + tid;
    float* ws = p.ws;

#define GS() { __threadfence(); gg.sync(); __threadfence(); }

    ph_zero(ws, gtid);
    GS();
    ph_prep(p, gtid);
    GS();
    // layer 1
    ph_proj<16, false>(p.x, ws + OFF_WC1, ws + OFF_DEG, ws + OFF_Y, 288, 5,
                       nullptr, nullptr, nullptr, nullptr, smem, bid, tid);
    GS();
    ph_egather<32>(ws + OFF_Y, p.eattr, p.ei, ws + OFF_H1, gtid);
    GS();
    ph_node<16, 32, false>(p.x, p.Wr1, p.br1, p.bias1, ws + OFF_H1, ws + OFF_ST1,
                           nullptr, nullptr, nullptr, nullptr, smem, bid, tid);
    GS();
    // layer 2 (BN1 folded)
    ph_proj<32, true>(ws + OFF_H1, ws + OFF_WC2, ws + OFF_DEG, ws + OFF_Y, 576, 9,
                      ws + OFF_ST1, p.bg1, p.bb1, p.a1, smem, bid, tid);
    GS();
    ph_egather<64>(ws + OFF_Y, p.eattr, p.ei, ws + OFF_H2, gtid);
    GS();
    ph_node<32, 64, true>(ws + OFF_H1, p.Wr2, p.br2, p.bias2, ws + OFF_H2, ws + OFF_ST2,
                          ws + OFF_ST1, p.bg1, p.bb1, p.a1, smem, bid, tid);
    GS();
    // layer 3 (BN2 folded)
    ph_proj<64, true>(ws + OFF_H2, ws + OFF_WC3, ws + OFF_DEG, ws + OFF_Y, 1152, 18,
                      ws + OFF_ST2, p.bg2, p.bb2, p.a2, smem, bid, tid);
    GS();
    ph_egather<128>(ws + OFF_Y, p.eattr, p.ei, ws + OFF_H3, gtid);
    GS();
    ph_node<64, 128, true>(ws + OFF_H2, p.Wr3, p.br3, p.bias3, ws + OFF_H3, ws + OFF_ST3,
                           ws + OFF_ST2, p.bg2, p.bb2, p.a2, smem, bid, tid);
    GS();
    // pool (BN3 folded) + head
    ph_pool(ws + OFF_H3, p.batch, p.Wi, p.bi, p.Wj, p.bj, ws + OFF_POOL,
            ws + OFF_ST3, p.bg3, p.bb3, p.a3, smem, bid, tid);
    GS();
    ph_final(ws + OFF_POOL, p.Wfc, p.bfc, p.out, smem, bid, tid);
#undef GS
}

// ================= fallback: one kernel per phase (non-cooperative) =================
__global__ __launch_bounds__(256) void kw_zero(Params p)  { ph_zero(p.ws, blockIdx.x * 256 + threadIdx.x); }
__global__ __launch_bounds__(256) void kw_prep(Params p)  { ph_prep(p, blockIdx.x * 256 + threadIdx.x); }
__global__ __launch_bounds__(256) void kw_proj1(Params p) { __shared__ float smem[9728];
    ph_proj<16, false>(p.x, p.ws + OFF_WC1, p.ws + OFF_DEG, p.ws + OFF_Y, 288, 5,
                       nullptr, nullptr, nullptr, nullptr, smem, blockIdx.x, threadIdx.x); }
__global__ __launch_bounds__(256) void kw_eg1(Params p)   { ph_egather<32>(p.ws + OFF_Y, p.eattr, p.ei, p.ws + OFF_H1, blockIdx.x * 256 + threadIdx.x); }
__global__ __launch_bounds__(256) void kw_node1(Params p) { __shared__ float smem[9728];
    ph_node<16, 32, false>(p.x, p.Wr1, p.br1, p.bias1, p.ws + OFF_H1, p.ws + OFF_ST1,
                           nullptr, nullptr, nullptr, nullptr, smem, blockIdx.x, threadIdx.x); }
__global__ __launch_bounds__(256) void kw_proj2(Params p) { __shared__ float smem[9728];
    ph_proj<32, true>(p.ws + OFF_H1, p.ws + OFF_WC2, p.ws + OFF_DEG, p.ws + OFF_Y, 576, 9,
                      p.ws + OFF_ST1, p.bg1, p.bb1, p.a1, smem, blockIdx.x, threadIdx.x); }
__global__ __launch_bounds__(256) void kw_eg2(Params p)   { ph_egather<64>(p.ws + OFF_Y, p.eattr, p.ei, p.ws + OFF_H2, blockIdx.x * 256 + threadIdx.x); }
__global__ __launch_bounds__(256) void kw_node2(Params p) { __shared__ float smem[9728];
    ph_node<32, 64, true>(p.ws + OFF_H1, p.Wr2, p.br2, p.bias2, p.ws + OFF_H2, p.ws + OFF_ST2,
                          p.ws + OFF_ST1, p.bg1, p.bb1, p.a1, smem, blockIdx.x, threadIdx.x); }
__global__ __launch_bounds__(256) void kw_proj3(Params p) { __shared__ float smem[9728];
    ph_proj<64, true>(p.ws + OFF_H2, p.ws + OFF_WC3, p.ws + OFF_DEG, p.ws + OFF_Y, 1152, 18,
                      p.ws + OFF_ST2, p.bg2, p.bb2, p.a2, smem, blockIdx.x, threadIdx.x); }
__global__ __launch_bounds__(256) void kw_eg3(Params p)   { ph_egather<128>(p.ws + OFF_Y, p.eattr, p.ei, p.ws + OFF_H3, blockIdx.x * 256 + threadIdx.x); }
__global__ __launch_bounds__(256) void kw_node3(Params p) { __shared__ float smem[9728];
    ph_node<64, 128, true>(p.ws + OFF_H2, p.Wr3, p.br3, p.bias3, p.ws + OFF_H3, p.ws + OFF_ST3,
                           p.ws + OFF_ST2, p.bg2, p.bb2, p.a2, smem, blockIdx.x, threadIdx.x); }
__global__ __launch_bounds__(256) void kw_pool(Params p)  { __shared__ float smem[9728];
    ph_pool(p.ws + OFF_H3, p.batch, p.Wi, p.bi, p.Wj, p.bj, p.ws + OFF_POOL,
            p.ws + OFF_ST3, p.bg3, p.bb3, p.a3, smem, blockIdx.x, threadIdx.x); }
__global__ __launch_bounds__(256) void kw_final(Params p) { __shared__ float smem[9728];
    ph_final(p.ws + OFF_POOL, p.Wfc, p.bfc, p.out, smem, blockIdx.x, threadIdx.x); }

extern "C" void kernel_launch(void* const* d_in, const int* in_sizes, int n_in,
                              void* d_out, int out_size, void* d_ws, size_t ws_size,
                              hipStream_t stream)
{
    (void)in_sizes; (void)n_in; (void)out_size; (void)ws_size;
    Params p;
    p.x     = (const float*)d_in[0];
    p.eattr = (const float*)d_in[1];
    p.ei    = (const int*)d_in[2];
    p.batch = (const int*)d_in[3];
    p.We1 = (const float*)d_in[4];  p.be1 = (const float*)d_in[5];
    p.bias1 = (const float*)d_in[6];
    p.Wr1 = (const float*)d_in[7];  p.br1 = (const float*)d_in[8];
    p.bg1 = (const float*)d_in[9];  p.bb1 = (const float*)d_in[10];
    p.a1  = (const float*)d_in[11];
    p.We2 = (const float*)d_in[12]; p.be2 = (const float*)d_in[13];
    p.bias2 = (const float*)d_in[14];
    p.Wr2 = (const float*)d_in[15]; p.br2 = (const float*)d_in[16];
    p.bg2 = (const float*)d_in[17]; p.bb2 = (const float*)d_in[18];
    p.a2  = (const float*)d_in[19];
    p.We3 = (const float*)d_in[20]; p.be3 = (const float*)d_in[21];
    p.bias3 = (const float*)d_in[22];
    p.Wr3 = (const float*)d_in[23]; p.br3 = (const float*)d_in[24];
    p.bg3 = (const float*)d_in[25]; p.bb3 = (const float*)d_in[26];
    p.a3  = (const float*)d_in[27];
    p.Wi  = (const float*)d_in[28]; p.bi  = (const float*)d_in[29];
    p.Wj  = (const float*)d_in[30]; p.bj  = (const float*)d_in[31];
    p.Wfc = (const float*)d_in[32]; p.bfc = (const float*)d_in[33];
    p.ws  = (float*)d_ws;
    p.out = (float*)d_out;

    void* args[] = { &p };
    hipError_t err = hipLaunchCooperativeKernel((void*)mega, dim3(NBLK), dim3(256),
                                                args, 0, stream);
    if (err != hipSuccess) {
        (void)hipGetLastError();   // clear sticky error, use fallback path
        kw_zero <<<NBLK, 256, 0, stream>>>(p);
        kw_prep <<<NBLK, 256, 0, stream>>>(p);
        kw_proj1<<<NBLK, 256, 0, stream>>>(p);
        kw_eg1  <<<NBLK, 256, 0, stream>>>(p);
        kw_node1<<<NBLK, 256, 0, stream>>>(p);
        kw_proj2<<<NBLK, 256, 0, stream>>>(p);
        kw_eg2  <<<NBLK, 256, 0, stream>>>(p);
        kw_node2<<<NBLK, 256, 0, stream>>>(p);
        kw_proj3<<<NBLK, 256, 0, stream>>>(p);
        kw_eg3  <<<NBLK, 256, 0, stream>>>(p);
        kw_node3<<<NBLK, 256, 0, stream>>>(p);
        kw_pool <<<NBLK, 256, 0, stream>>>(p);
        kw_final<<<NBLK, 256, 0, stream>>>(p);
    }
}

// Round 3
// 329.576 us; speedup vs baseline: 5.4472x; 5.4472x over previous
//
#include <hip/hip_runtime.h>
#include <math.h>

#define NN 4096
#define NE 16384
#define NG 64

// ---- ws layout (float offsets), zero-region first ----
#define OFF_DEG    0         // 4096 f   (src out-degree, float)
#define OFF_CNT    4096      // 4096 i   (dst in-degree counts / scatter cursor)
#define OFF_ST1    8192      // 64
#define OFF_ST2    8256      // 128
#define OFF_ST3    8384      // 256
#define OFF_POOL   8640      // 64*128 = 8192
#define ZERO_FLOATS 16832    // zero everything above only
#define OFF_ROW    16832     // 4097 i   (CSR rowptr by dst)
#define OFF_ELIST  20992     // 16384 i  (packed src<<14 | e)
#define OFF_WC1    37376     // 16*288  = 4608
#define OFF_WC2    41984     // 32*576  = 18432
#define OFF_WC3    60416     // 64*1152 = 73728
#define OFF_H1     134144    // 4096*32
#define OFF_H2     265216    // 4096*64
#define OFF_H3     527360    // 4096*128
#define OFF_Y      1051648   // 4096*1152 (reused across layers)

// ---------------- prep: Wcat build + deg(src) + cnt(dst) ----------------
// Wcat[i*(9*COUT) + f*COUT + o] = f<8 ? We[f*CIN*COUT + o*CIN + i] : be[o*CIN + i]
__device__ __forceinline__ void tr_wcat(const float* We, const float* be,
                                        float* Wcat, int CIN, int COUT, int t) {
    int nine = 9 * COUT;
    int i = t / nine; int r = t - i * nine;
    int f = r / COUT; int o = r - f * COUT;
    Wcat[t] = (f < 8) ? We[f * CIN * COUT + o * CIN + i] : be[o * CIN + i];
}

__global__ __launch_bounds__(256) void k_prep(
    const float* __restrict__ We1, const float* __restrict__ be1,
    const float* __restrict__ We2, const float* __restrict__ be2,
    const float* __restrict__ We3, const float* __restrict__ be3,
    const int* __restrict__ ei, float* __restrict__ ws)
{
    int t = blockIdx.x * 256 + threadIdx.x;
    if (t < 4608)  { tr_wcat(We1, be1, ws + OFF_WC1, 16, 32, t); return; }
    t -= 4608;
    if (t < 18432) { tr_wcat(We2, be2, ws + OFF_WC2, 32, 64, t); return; }
    t -= 18432;
    if (t < 73728) { tr_wcat(We3, be3, ws + OFF_WC3, 64, 128, t); return; }
    t -= 73728;
    if (t < NE) {
        atomicAdd(&ws[OFF_DEG + ei[t]], 1.0f);                 // src out-degree
        atomicAdd(&((int*)(ws + OFF_CNT))[ei[NE + t]], 1);     // dst in-degree
    }
}

// ---------------- scan + scatter: CSR by dst (single block) ----------------
__global__ __launch_bounds__(1024) void k_scan(const int* __restrict__ ei,
                                               float* __restrict__ ws)
{
    __shared__ int s[1024];
    int* cnt    = (int*)(ws + OFF_CNT);
    int* rowptr = (int*)(ws + OFF_ROW);
    int* elist  = (int*)(ws + OFF_ELIST);
    const int tid = threadIdx.x;

    int4 c = ((const int4*)cnt)[tid];
    int mysum = c.x + c.y + c.z + c.w;
    s[tid] = mysum;
    __syncthreads();
    for (int off = 1; off < 1024; off <<= 1) {
        int v = (tid >= off) ? s[tid - off] : 0;
        __syncthreads();
        s[tid] += v;
        __syncthreads();
    }
    int base = s[tid] - mysum;               // exclusive
    rowptr[4 * tid + 0] = base;
    rowptr[4 * tid + 1] = base + c.x;
    rowptr[4 * tid + 2] = base + c.x + c.y;
    rowptr[4 * tid + 3] = base + c.x + c.y + c.z;
    if (tid == 1023) rowptr[4096] = s[1023];
    ((int4*)cnt)[tid] = make_int4(0, 0, 0, 0);   // reset cursor
    __syncthreads();
    for (int e = tid; e < NE; e += 1024) {
        int dst = ei[NE + e];
        int pos = rowptr[dst] + atomicAdd(&cnt[dst], 1);
        elist[pos] = (ei[e] << 14) | e;          // src(12b) | e(14b)
    }
}

// ---------------- proj GEMM: Y[n,col] = norm[n] * sum_i bnp(A[n,i]) * B[i,col] ----------------
template<int K, bool BN>
__global__ __launch_bounds__(256) void k_proj(
    const float* __restrict__ A, const float* __restrict__ Bm,
    const float* __restrict__ deg, float* __restrict__ Y, int Ncols,
    const float* __restrict__ st, const float* __restrict__ g,
    const float* __restrict__ b, const float* __restrict__ a)
{
    __shared__ float sA[K][68];
    __shared__ float sB[K][68];
    __shared__ float sS[K];
    __shared__ float sT[K];
    const int tid = threadIdx.x;
    const int m0 = blockIdx.x * 64;
    const int n0 = blockIdx.y * 64;

    float al = 0.f;
    if constexpr (BN) {
        if (tid < K) {
            float mean = st[tid] * (1.f / NN);
            float var  = st[K + tid] * (1.f / NN) - mean * mean;
            var = fmaxf(var, 0.f);
            float s = rsqrtf(var + 1e-5f) * g[tid];
            sS[tid] = s;
            sT[tid] = b[tid] - mean * s;
        }
        al = a[0];
        __syncthreads();
    }

    for (int t = tid; t < 64 * K; t += 256) {
        int m = t / K, i = t - m * K;
        float v = A[(m0 + m) * K + i];
        if constexpr (BN) {
            v = fmaf(v, sS[i], sT[i]);
            v = v >= 0.f ? v : al * v;
        }
        sA[i][m] = v;
    }
    for (int t = tid; t < 64 * K; t += 256) {
        int i = t >> 6, n = t & 63;
        int col = n0 + n;
        sB[i][n] = (col < Ncols) ? Bm[i * Ncols + col] : 0.f;
    }
    __syncthreads();

    const int tn = tid & 15, tm = tid >> 4;
    float acc[4][4] = {{0.f}};
#pragma unroll 8
    for (int i = 0; i < K; ++i) {
        float4 av = *(const float4*)&sA[i][tm * 4];
        float4 bv = *(const float4*)&sB[i][tn * 4];
        acc[0][0] += av.x * bv.x; acc[0][1] += av.x * bv.y; acc[0][2] += av.x * bv.z; acc[0][3] += av.x * bv.w;
        acc[1][0] += av.y * bv.x; acc[1][1] += av.y * bv.y; acc[1][2] += av.y * bv.z; acc[1][3] += av.y * bv.w;
        acc[2][0] += av.z * bv.x; acc[2][1] += av.z * bv.y; acc[2][2] += av.z * bv.z; acc[2][3] += av.z * bv.w;
        acc[3][0] += av.w * bv.x; acc[3][1] += av.w * bv.y; acc[3][2] += av.w * bv.z; acc[3][3] += av.w * bv.w;
    }

#pragma unroll
    for (int mm = 0; mm < 4; ++mm) {
        int m = m0 + tm * 4 + mm;
        float d = deg[m];
        float nrm = d > 0.f ? 1.f / d : 0.f;
#pragma unroll
        for (int nn = 0; nn < 4; ++nn) {
            int col = n0 + tn * 4 + nn;
            if (col < Ncols) Y[(size_t)m * Ncols + col] = acc[mm][nn] * nrm;
        }
    }
}

// ---------------- gnode: fused edge-gather (CSR, no atomics) + residual + BN stats ----------------
// block owns NB dst nodes; thread (o, nl) handles KN nodes; h written exactly once.
template<int CIN, int COUT, int NB, bool BN>
__global__ __launch_bounds__(256) void k_gnode(
    const float* __restrict__ xin, const float* __restrict__ Wr,
    const float* __restrict__ br, const float* __restrict__ bias,
    const float* __restrict__ Y, const float* __restrict__ eattr,
    const int* __restrict__ rowptr, const int* __restrict__ elist,
    float* __restrict__ h, float* __restrict__ st_out,
    const float* __restrict__ st_in, const float* __restrict__ g,
    const float* __restrict__ b, const float* __restrict__ a)
{
    constexpr int NL = 256 / COUT;
    constexpr int KN = NB / NL;
    constexpr int CINP = CIN | 1;
    __shared__ float sWr[CIN * COUT];
    __shared__ float sX[NB * CINP];
    __shared__ float sred[256];
    __shared__ float sS[CIN];
    __shared__ float sT[CIN];
    const int tid = threadIdx.x;
    const int nbase = blockIdx.x * NB;

    if constexpr (BN) {
        if (tid < CIN) {
            float mean = st_in[tid] * (1.f / NN);
            float var  = st_in[CIN + tid] * (1.f / NN) - mean * mean;
            var = fmaxf(var, 0.f);
            float s = rsqrtf(var + 1e-5f) * g[tid];
            sS[tid] = s;
            sT[tid] = b[tid] - mean * s;
        }
    }
    for (int t = tid; t < CIN * COUT; t += 256) sWr[t] = Wr[t];
    __syncthreads();
    float al = 0.f;
    if constexpr (BN) al = a[0];

    for (int t = tid; t < NB * CIN; t += 256) {
        int r = t / CIN, i = t - r * CIN;
        float v = xin[(nbase + r) * CIN + i];
        if constexpr (BN) {
            v = fmaf(v, sS[i], sT[i]);
            v = v >= 0.f ? v : al * v;
        }
        sX[r * CINP + i] = v;
    }
    __syncthreads();

    const int o = tid % COUT;
    const int nl = tid / COUT;
    const float addc = bias[o] + br[o];
    float sum = 0.f, sumsq = 0.f;
#pragma unroll
    for (int k = 0; k < KN; ++k) {
        int r = nl * KN + k;
        int gn = nbase + r;
        float acc = addc;
        for (int i = 0; i < CIN; ++i)
            acc += sX[r * CINP + i] * sWr[i * COUT + o];
        int e0 = rowptr[gn], e1 = rowptr[gn + 1];
        for (int j = e0; j < e1; ++j) {
            int pk = elist[j];
            int src = pk >> 14;
            int e = pk & 16383;
            const float* y = Y + (size_t)src * (9 * COUT);
            const float* ea = eattr + e * 8;
            float m = y[8 * COUT + o];      // be-term
#pragma unroll
            for (int f = 0; f < 8; ++f) m += ea[f] * y[f * COUT + o];
            acc += m;
        }
        h[gn * COUT + o] = acc;
        sum += acc; sumsq += acc * acc;
    }
    sred[tid] = sum;
    __syncthreads();
    if (tid < COUT) {
        float s = 0.f;
        for (int q = 0; q < NL; ++q) s += sred[q * COUT + tid];
        atomicAdd(&st_out[tid], s);
    }
    __syncthreads();
    sred[tid] = sumsq;
    __syncthreads();
    if (tid < COUT) {
        float s = 0.f;
        for (int q = 0; q < NL; ++q) s += sred[q * COUT + tid];
        atomicAdd(&st_out[COUT + tid], s);
    }
}

// ---------------- pool: BN3+PReLU3 on load, gated attention, scatter per graph ----------------
__global__ __launch_bounds__(256) void k_pool(
    const float* __restrict__ h3, const int* __restrict__ batch,
    const float* __restrict__ Wi, const float* __restrict__ bi,
    const float* __restrict__ Wj, const float* __restrict__ bj,
    float* __restrict__ pooled,
    const float* __restrict__ st, const float* __restrict__ g,
    const float* __restrict__ b, const float* __restrict__ a)
{
    constexpr int KN = 8, NB = 16;
    __shared__ float sH[NB * 128];
    __shared__ int sB[NB];
    __shared__ float sS[128];
    __shared__ float sT[128];
    const int tid = threadIdx.x;
    const int nbase = blockIdx.x * NB;

    if (tid < 128) {
        float mean = st[tid] * (1.f / NN);
        float var  = st[128 + tid] * (1.f / NN) - mean * mean;
        var = fmaxf(var, 0.f);
        float s = rsqrtf(var + 1e-5f) * g[tid];
        sS[tid] = s;
        sT[tid] = b[tid] - mean * s;
    }
    if (tid < NB) sB[tid] = batch[nbase + tid];
    __syncthreads();
    const float al = a[0];

    for (int t = tid; t < NB * 128; t += 256) {
        int c = t & 127;
        float v = h3[nbase * 128 + t];
        v = fmaf(v, sS[c], sT[c]);
        v = v >= 0.f ? v : al * v;
        sH[t] = v;
    }
    __syncthreads();

    const int o = tid & 127, nl = tid >> 7;
    float gacc[KN], facc[KN];
#pragma unroll
    for (int k = 0; k < KN; ++k) { gacc[k] = 0.f; facc[k] = 0.f; }
    for (int i = 0; i < 128; ++i) {
        float wi = Wi[i * 128 + o], wj = Wj[i * 128 + o];
#pragma unroll
        for (int k = 0; k < KN; ++k) {
            float hv = sH[(nl * KN + k) * 128 + i];
            gacc[k] += hv * wi;
            facc[k] += hv * wj;
        }
    }
    float bio = bi[o], bjo = bj[o];
#pragma unroll
    for (int k = 0; k < KN; ++k) {
        int r = nl * KN + k;
        float gate = 1.f / (1.f + expf(-(gacc[k] + bio)));
        float feat = tanhf(facc[k] + bjo);
        atomicAdd(&pooled[sB[r] * 128 + o], gate * feat);
    }
}

// ---------------- final: tanh(pooled) @ Wfc + bfc, split halves ----------------
__global__ __launch_bounds__(256) void k_final(
    const float* __restrict__ pooled, const float* __restrict__ Wfc,
    const float* __restrict__ bfc, float* __restrict__ out)
{
    __shared__ float sP[128];
    const int g = blockIdx.x, c = threadIdx.x;
    if (c < 128) sP[c] = tanhf(pooled[g * 128 + c]);
    __syncthreads();
    float z = bfc[c];
    for (int i = 0; i < 128; ++i) z += sP[i] * Wfc[i * 256 + c];
    int oidx = (c < 128) ? (g * 128 + c) : (NG * 128 + g * 128 + (c - 128));
    out[oidx] = z;
}

extern "C" void kernel_launch(void* const* d_in, const int* in_sizes, int n_in,
                              void* d_out, int out_size, void* d_ws, size_t ws_size,
                              hipStream_t stream)
{
    (void)in_sizes; (void)n_in; (void)out_size; (void)ws_size;
    const float* x     = (const float*)d_in[0];
    const float* eattr = (const float*)d_in[1];
    const int*   ei    = (const int*)d_in[2];
    const int*   batch = (const int*)d_in[3];
    const float* We1 = (const float*)d_in[4];
    const float* be1 = (const float*)d_in[5];
    const float* bias1 = (const float*)d_in[6];
    const float* Wr1 = (const float*)d_in[7];
    const float* br1 = (const float*)d_in[8];
    const float* bg1 = (const float*)d_in[9];
    const float* bb1 = (const float*)d_in[10];
    const float* a1  = (const float*)d_in[11];
    const float* We2 = (const float*)d_in[12];
    const float* be2 = (const float*)d_in[13];
    const float* bias2 = (const float*)d_in[14];
    const float* Wr2 = (const float*)d_in[15];
    const float* br2 = (const float*)d_in[16];
    const float* bg2 = (const float*)d_in[17];
    const float* bb2 = (const float*)d_in[18];
    const float* a2  = (const float*)d_in[19];
    const float* We3 = (const float*)d_in[20];
    const float* be3 = (const float*)d_in[21];
    const float* bias3 = (const float*)d_in[22];
    const float* Wr3 = (const float*)d_in[23];
    const float* br3 = (const float*)d_in[24];
    const float* bg3 = (const float*)d_in[25];
    const float* bb3 = (const float*)d_in[26];
    const float* a3  = (const float*)d_in[27];
    const float* Wi  = (const float*)d_in[28];
    const float* bi  = (const float*)d_in[29];
    const float* Wj  = (const float*)d_in[30];
    const float* bj  = (const float*)d_in[31];
    const float* Wfc = (const float*)d_in[32];
    const float* bfc = (const float*)d_in[33];
    float* ws  = (float*)d_ws;
    float* out = (float*)d_out;
    const int* rowptr = (const int*)(ws + OFF_ROW);
    const int* elist  = (const int*)(ws + OFF_ELIST);

    hipMemsetAsync(d_ws, 0, (size_t)ZERO_FLOATS * sizeof(float), stream);
    k_prep<<<506, 256, 0, stream>>>(We1, be1, We2, be2, We3, be3, ei, ws);
    k_scan<<<1, 1024, 0, stream>>>(ei, ws);

    // layer 1: cin=16, cout=32, Ncols=288 (no BN on x)
    k_proj<16, false><<<dim3(64, 5), 256, 0, stream>>>(
        x, ws + OFF_WC1, ws + OFF_DEG, ws + OFF_Y, 288,
        nullptr, nullptr, nullptr, nullptr);
    k_gnode<16, 32, 8, false><<<NN / 8, 256, 0, stream>>>(
        x, Wr1, br1, bias1, ws + OFF_Y, eattr, rowptr, elist,
        ws + OFF_H1, ws + OFF_ST1, nullptr, nullptr, nullptr, nullptr);

    // layer 2: cin=32, cout=64, Ncols=576 (BN1 folded)
    k_proj<32, true><<<dim3(64, 9), 256, 0, stream>>>(
        ws + OFF_H1, ws + OFF_WC2, ws + OFF_DEG, ws + OFF_Y, 576,
        ws + OFF_ST1, bg1, bb1, a1);
    k_gnode<32, 64, 8, true><<<NN / 8, 256, 0, stream>>>(
        ws + OFF_H1, Wr2, br2, bias2, ws + OFF_Y, eattr, rowptr, elist,
        ws + OFF_H2, ws + OFF_ST2, ws + OFF_ST1, bg1, bb1, a1);

    // layer 3: cin=64, cout=128, Ncols=1152 (BN2 folded)
    k_proj<64, true><<<dim3(64, 18), 256, 0, stream>>>(
        ws + OFF_H2, ws + OFF_WC3, ws + OFF_DEG, ws + OFF_Y, 1152,
        ws + OFF_ST2, bg2, bb2, a2);
    k_gnode<64, 128, 8, true><<<NN / 8, 256, 0, stream>>>(
        ws + OFF_H2, Wr3, br3, bias3, ws + OFF_Y, eattr, rowptr, elist,
        ws + OFF_H3, ws + OFF_ST3, ws + OFF_ST2, bg2, bb2, a2);

    // pool (BN3 folded) + head
    k_pool<<<NN / 16, 256, 0, stream>>>(ws + OFF_H3, batch, Wi, bi, Wj, bj, ws + OFF_POOL,
                                        ws + OFF_ST3, bg3, bb3, a3);
    k_final<<<NG, 256, 0, stream>>>(ws + OFF_POOL, Wfc, bfc, out);
}

// Round 4
// 276.321 us; speedup vs baseline: 6.4971x; 1.1927x over previous
//
#include <hip/hip_runtime.h>
#include <math.h>

#define NN 4096
#define NE 16384
#define NG 64

// ---- ws layout (float offsets) ----
#define OFF_DEG   0         // 4096
#define OFF_H1    4096      // 4096*32
#define OFF_H2    135168    // 4096*64
#define OFF_H3    397312    // 4096*128
#define OFF_ST1   921600    // 64
#define OFF_ST2   921664    // 128
#define OFF_ST3   921792    // 256
#define OFF_POOL  922048    // 64*128 (unused now, kept for layout stability)
#define OFF_WC1   930240    // 16*288  = 4608
#define OFF_WC2   934848    // 32*576  = 18432
#define OFF_WC3   953280    // 64*1152 = 73728
#define OFF_Y     1027008   // 4096*1152 = 4718592 (reused across layers)
#define OFF_GR    5745600   // 65 ints (graph->node range boundaries)
#define ZERO_FLOATS 930240  // zero deg/h/stats/pool only

// ---------------- prep: Wcat build + degree + graph ranges ----------------
// Wcat[i*(9*COUT) + f*COUT + o] = f<8 ? We[f*CIN*COUT + o*CIN + i] : be[o*CIN + i]
__device__ __forceinline__ void tr_wcat(const float* We, const float* be,
                                        float* Wcat, int CIN, int COUT, int t) {
    int nine = 9 * COUT;
    int i = t / nine; int r = t - i * nine;
    int f = r / COUT; int o = r - f * COUT;
    Wcat[t] = (f < 8) ? We[f * CIN * COUT + o * CIN + i] : be[o * CIN + i];
}

__global__ __launch_bounds__(256) void k_prep(
    const float* __restrict__ We1, const float* __restrict__ be1,
    const float* __restrict__ We2, const float* __restrict__ be2,
    const float* __restrict__ We3, const float* __restrict__ be3,
    const int* __restrict__ ei, const int* __restrict__ batch,
    float* __restrict__ ws)
{
    int t = blockIdx.x * 256 + threadIdx.x;
    if (t < 4608)  { tr_wcat(We1, be1, ws + OFF_WC1, 16, 32, t); return; }
    t -= 4608;
    if (t < 18432) { tr_wcat(We2, be2, ws + OFF_WC2, 32, 64, t); return; }
    t -= 18432;
    if (t < 73728) { tr_wcat(We3, be3, ws + OFF_WC3, 64, 128, t); return; }
    t -= 73728;
    if (t < NE)    { atomicAdd(&ws[OFF_DEG + ei[t]], 1.0f); return; }
    t -= NE;
    if (t < NN) {
        // batch is sorted; gr[g] = first node index with batch[i] >= g
        int* gr = (int*)(ws + OFF_GR);
        int b1 = batch[t];
        int b0 = (t == 0) ? -1 : batch[t - 1];
        for (int g = b0 + 1; g <= b1; ++g) gr[g] = t;
        if (t == NN - 1)
            for (int g = b1 + 1; g <= NG; ++g) gr[g] = NN;
    }
}

// ---------------- proj GEMM: Y[n,col] = norm[n] * sum_i bnp(A[n,i]) * B[i,col] ----------------
// BM=64, BN=64, 256 threads, 4x4 per thread, K fully staged in LDS.
// BN=true: apply batchnorm(st/g/b) + PReLU(a) to A elements on load.
template<int K, bool BN>
__global__ __launch_bounds__(256) void k_proj(
    const float* __restrict__ A, const float* __restrict__ Bm,
    const float* __restrict__ deg, float* __restrict__ Y, int Ncols,
    const float* __restrict__ st, const float* __restrict__ g,
    const float* __restrict__ b, const float* __restrict__ a)
{
    __shared__ float sA[K][68];
    __shared__ float sB[K][68];
    __shared__ float sS[K];
    __shared__ float sT[K];
    const int tid = threadIdx.x;
    const int m0 = blockIdx.x * 64;
    const int n0 = blockIdx.y * 64;

    float al = 0.f;
    if constexpr (BN) {
        if (tid < K) {
            float mean = st[tid] * (1.f / NN);
            float var  = st[K + tid] * (1.f / NN) - mean * mean;
            var = fmaxf(var, 0.f);
            float s = rsqrtf(var + 1e-5f) * g[tid];
            sS[tid] = s;
            sT[tid] = b[tid] - mean * s;
        }
        al = a[0];
        __syncthreads();
    }

    for (int t = tid; t < 64 * K; t += 256) {
        int m = t / K, i = t - m * K;
        float v = A[(m0 + m) * K + i];
        if constexpr (BN) {
            v = fmaf(v, sS[i], sT[i]);
            v = v >= 0.f ? v : al * v;
        }
        sA[i][m] = v;
    }
    for (int t = tid; t < 64 * K; t += 256) {
        int i = t >> 6, n = t & 63;
        int col = n0 + n;
        sB[i][n] = (col < Ncols) ? Bm[i * Ncols + col] : 0.f;
    }
    __syncthreads();

    const int tn = tid & 15, tm = tid >> 4;
    float acc[4][4] = {{0.f}};
#pragma unroll 8
    for (int i = 0; i < K; ++i) {
        float4 av = *(const float4*)&sA[i][tm * 4];
        float4 bv = *(const float4*)&sB[i][tn * 4];
        acc[0][0] += av.x * bv.x; acc[0][1] += av.x * bv.y; acc[0][2] += av.x * bv.z; acc[0][3] += av.x * bv.w;
        acc[1][0] += av.y * bv.x; acc[1][1] += av.y * bv.y; acc[1][2] += av.y * bv.z; acc[1][3] += av.y * bv.w;
        acc[2][0] += av.z * bv.x; acc[2][1] += av.z * bv.y; acc[2][2] += av.z * bv.z; acc[2][3] += av.z * bv.w;
        acc[3][0] += av.w * bv.x; acc[3][1] += av.w * bv.y; acc[3][2] += av.w * bv.z; acc[3][3] += av.w * bv.w;
    }

#pragma unroll
    for (int mm = 0; mm < 4; ++mm) {
        int m = m0 + tm * 4 + mm;
        float d = deg[m];
        float nrm = d > 0.f ? 1.f / d : 0.f;
#pragma unroll
        for (int nn = 0; nn < 4; ++nn) {
            int col = n0 + tn * 4 + nn;
            if (col < Ncols) Y[(size_t)m * Ncols + col] = acc[mm][nn] * nrm;
        }
    }
}

// ---------------- per-edge gather: h[dst,o] += sum_f ea'[e,f] * Y[src, f*COUT+o] ----------------
// round-0 proven version: one scalar atomic per thread, fully parallel.
template<int COUT>
__global__ __launch_bounds__(256) void k_egather(
    const float* __restrict__ Y, const float* __restrict__ eattr,
    const int* __restrict__ ei, float* __restrict__ h)
{
    int idx = blockIdx.x * 256 + threadIdx.x;
    int e = idx / COUT;
    int o = idx - e * COUT;
    int src = ei[e], dst = ei[NE + e];
    const float* y = Y + (size_t)src * (9 * COUT);
    const float* ea = eattr + e * 8;
    float acc = y[8 * COUT + o];      // be-term, ea' = 1
#pragma unroll
    for (int f = 0; f < 8; ++f) acc += ea[f] * y[f * COUT + o];
    atomicAdd(&h[dst * COUT + o], acc);
}

// ---------------- node: residual + bias, accumulate BN stats ----------------
// BN=true: xin is pre-BN h of previous layer -> apply bn(st_in/g/b)+PReLU(a) on load.
template<int CIN, int COUT, int KN, bool BN>
__global__ __launch_bounds__(256) void k_node(
    const float* __restrict__ xin, const float* __restrict__ Wr,
    const float* __restrict__ br, const float* __restrict__ bias,
    float* __restrict__ h, float* __restrict__ st_out,
    const float* __restrict__ st_in, const float* __restrict__ g,
    const float* __restrict__ b, const float* __restrict__ a)
{
    constexpr int NL = 256 / COUT;
    constexpr int NB = NL * KN;
    constexpr int CINP = CIN | 1;
    __shared__ float sWr[CIN * COUT];
    __shared__ float sX[NB * CINP];
    __shared__ float sred[256];
    __shared__ float sS[CIN];
    __shared__ float sT[CIN];
    const int tid = threadIdx.x;
    const int nbase = blockIdx.x * NB;

    if constexpr (BN) {
        if (tid < CIN) {
            float mean = st_in[tid] * (1.f / NN);
            float var  = st_in[CIN + tid] * (1.f / NN) - mean * mean;
            var = fmaxf(var, 0.f);
            float s = rsqrtf(var + 1e-5f) * g[tid];
            sS[tid] = s;
            sT[tid] = b[tid] - mean * s;
        }
    }
    for (int t = tid; t < CIN * COUT; t += 256) sWr[t] = Wr[t];
    __syncthreads();
    float al = 0.f;
    if constexpr (BN) al = a[0];

    for (int t = tid; t < NB * CIN; t += 256) {
        int r = t / CIN, i = t - r * CIN;
        float v = xin[(nbase + r) * CIN + i];
        if constexpr (BN) {
            v = fmaf(v, sS[i], sT[i]);
            v = v >= 0.f ? v : al * v;
        }
        sX[r * CINP + i] = v;
    }
    __syncthreads();

    const int o = tid % COUT;
    const int nl = tid / COUT;
    const float addc = bias[o] + br[o];
    float sum = 0.f, sumsq = 0.f;
    for (int k = 0; k < KN; ++k) {
        int r = nl * KN + k;
        float acc = addc;
        for (int i = 0; i < CIN; ++i)
            acc += sX[r * CINP + i] * sWr[i * COUT + o];
        int gi = (nbase + r) * COUT + o;
        float hv = h[gi] + acc;
        h[gi] = hv;
        sum += hv; sumsq += hv * hv;
    }
    sred[tid] = sum;
    __syncthreads();
    if (tid < COUT) {
        float s = 0.f;
        for (int q = 0; q < NL; ++q) s += sred[q * COUT + tid];
        atomicAdd(&st_out[tid], s);
    }
    __syncthreads();
    sred[tid] = sumsq;
    __syncthreads();
    if (tid < COUT) {
        float s = 0.f;
        for (int q = 0; q < NL; ++q) s += sred[q * COUT + tid];
        atomicAdd(&st_out[COUT + tid], s);
    }
}

// ---------------- poolfinal: BN3+PReLU3 on load, gated pooling per graph, head ----------------
// batch is sorted -> graph g owns contiguous node range [gr[g], gr[g+1]).
// One block per graph; no global atomics; head fused.
__global__ __launch_bounds__(256) void k_poolfinal(
    const float* __restrict__ h3, const float* __restrict__ gr_f,
    const float* __restrict__ Wi, const float* __restrict__ bi,
    const float* __restrict__ Wj, const float* __restrict__ bj,
    const float* __restrict__ Wfc, const float* __restrict__ bfc,
    const float* __restrict__ st, const float* __restrict__ g,
    const float* __restrict__ b, const float* __restrict__ a,
    float* __restrict__ out)
{
    __shared__ float sH[16 * 128];
    __shared__ float sS[128];
    __shared__ float sT[128];
    __shared__ float sred[256];
    __shared__ float sP[128];
    const int tid = threadIdx.x;
    const int gid = blockIdx.x;
    const int* gr = (const int*)gr_f;
    const int r0 = gr[gid], r1 = gr[gid + 1];

    if (tid < 128) {
        float mean = st[tid] * (1.f / NN);
        float var  = st[128 + tid] * (1.f / NN) - mean * mean;
        var = fmaxf(var, 0.f);
        float s = rsqrtf(var + 1e-5f) * g[tid];
        sS[tid] = s;
        sT[tid] = b[tid] - mean * s;
    }
    __syncthreads();
    const float al = a[0];
    const int o = tid & 127, nl = tid >> 7;
    const float bio = bi[o], bjo = bj[o];
    float psum = 0.f;

    for (int base = r0; base < r1; base += 16) {
        __syncthreads();   // WAR on sH
        int cnt = min(16, r1 - base);
        for (int t = tid; t < cnt * 128; t += 256) {
            int c = t & 127;
            float v = h3[base * 128 + t];
            v = fmaf(v, sS[c], sT[c]);
            v = v >= 0.f ? v : al * v;
            sH[t] = v;
        }
        __syncthreads();
        float gacc[8], facc[8];
#pragma unroll
        for (int k = 0; k < 8; ++k) { gacc[k] = 0.f; facc[k] = 0.f; }
        for (int i = 0; i < 128; ++i) {
            float wi = Wi[i * 128 + o], wj = Wj[i * 128 + o];
#pragma unroll
            for (int k = 0; k < 8; ++k) {
                float hv = sH[(nl * 8 + k) * 128 + i];
                gacc[k] += hv * wi;
                facc[k] += hv * wj;
            }
        }
#pragma unroll
        for (int k = 0; k < 8; ++k) {
            int r = base + nl * 8 + k;
            if (r < r1) {
                float gate = 1.f / (1.f + expf(-(gacc[k] + bio)));
                float feat = tanhf(facc[k] + bjo);
                psum += gate * feat;
            }
        }
    }

    sred[tid] = psum;
    __syncthreads();
    if (tid < 128) sP[tid] = tanhf(sred[tid] + sred[128 + tid]);
    __syncthreads();
    float z = bfc[tid];
    for (int i = 0; i < 128; ++i) z += sP[i] * Wfc[i * 256 + tid];
    int oidx = (tid < 128) ? (gid * 128 + tid) : (NG * 128 + gid * 128 + (tid - 128));
    out[oidx] = z;
}

extern "C" void kernel_launch(void* const* d_in, const int* in_sizes, int n_in,
                              void* d_out, int out_size, void* d_ws, size_t ws_size,
                              hipStream_t stream)
{
    (void)in_sizes; (void)n_in; (void)out_size; (void)ws_size;
    const float* x     = (const float*)d_in[0];
    const float* eattr = (const float*)d_in[1];
    const int*   ei    = (const int*)d_in[2];
    const int*   batch = (const int*)d_in[3];
    const float* We1 = (const float*)d_in[4];
    const float* be1 = (const float*)d_in[5];
    const float* bias1 = (const float*)d_in[6];
    const float* Wr1 = (const float*)d_in[7];
    const float* br1 = (const float*)d_in[8];
    const float* bg1 = (const float*)d_in[9];
    const float* bb1 = (const float*)d_in[10];
    const float* a1  = (const float*)d_in[11];
    const float* We2 = (const float*)d_in[12];
    const float* be2 = (const float*)d_in[13];
    const float* bias2 = (const float*)d_in[14];
    const float* Wr2 = (const float*)d_in[15];
    const float* br2 = (const float*)d_in[16];
    const float* bg2 = (const float*)d_in[17];
    const float* bb2 = (const float*)d_in[18];
    const float* a2  = (const float*)d_in[19];
    const float* We3 = (const float*)d_in[20];
    const float* be3 = (const float*)d_in[21];
    const float* bias3 = (const float*)d_in[22];
    const float* Wr3 = (const float*)d_in[23];
    const float* br3 = (const float*)d_in[24];
    const float* bg3 = (const float*)d_in[25];
    const float* bb3 = (const float*)d_in[26];
    const float* a3  = (const float*)d_in[27];
    const float* Wi  = (const float*)d_in[28];
    const float* bi  = (const float*)d_in[29];
    const float* Wj  = (const float*)d_in[30];
    const float* bj  = (const float*)d_in[31];
    const float* Wfc = (const float*)d_in[32];
    const float* bfc = (const float*)d_in[33];
    float* ws  = (float*)d_ws;
    float* out = (float*)d_out;

    hipMemsetAsync(d_ws, 0, (size_t)ZERO_FLOATS * sizeof(float), stream);
    k_prep<<<458, 256, 0, stream>>>(We1, be1, We2, be2, We3, be3, ei, batch, ws);

    // layer 1: cin=16, cout=32, Ncols=288 (no BN on x)
    k_proj<16, false><<<dim3(64, 5), 256, 0, stream>>>(
        x, ws + OFF_WC1, ws + OFF_DEG, ws + OFF_Y, 288,
        nullptr, nullptr, nullptr, nullptr);
    k_egather<32><<<NE * 32 / 256, 256, 0, stream>>>(ws + OFF_Y, eattr, ei, ws + OFF_H1);
    k_node<16, 32, 8, false><<<NN / 64, 256, 0, stream>>>(
        x, Wr1, br1, bias1, ws + OFF_H1, ws + OFF_ST1,
        nullptr, nullptr, nullptr, nullptr);

    // layer 2: cin=32, cout=64, Ncols=576 (BN1 folded into loads of h1)
    k_proj<32, true><<<dim3(64, 9), 256, 0, stream>>>(
        ws + OFF_H1, ws + OFF_WC2, ws + OFF_DEG, ws + OFF_Y, 576,
        ws + OFF_ST1, bg1, bb1, a1);
    k_egather<64><<<NE * 64 / 256, 256, 0, stream>>>(ws + OFF_Y, eattr, ei, ws + OFF_H2);
    k_node<32, 64, 8, true><<<NN / 32, 256, 0, stream>>>(
        ws + OFF_H1, Wr2, br2, bias2, ws + OFF_H2, ws + OFF_ST2,
        ws + OFF_ST1, bg1, bb1, a1);

    // layer 3: cin=64, cout=128, Ncols=1152 (BN2 folded)
    k_proj<64, true><<<dim3(64, 18), 256, 0, stream>>>(
        ws + OFF_H2, ws + OFF_WC3, ws + OFF_DEG, ws + OFF_Y, 1152,
        ws + OFF_ST2, bg2, bb2, a2);
    k_egather<128><<<NE * 128 / 256, 256, 0, stream>>>(ws + OFF_Y, eattr, ei, ws + OFF_H3);
    k_node<64, 128, 8, true><<<NN / 16, 256, 0, stream>>>(
        ws + OFF_H2, Wr3, br3, bias3, ws + OFF_H3, ws + OFF_ST3,
        ws + OFF_ST2, bg2, bb2, a2);

    // pooling + head fused (BN3 folded), one block per graph, no atomics
    k_poolfinal<<<NG, 256, 0, stream>>>(
        ws + OFF_H3, ws + OFF_GR, Wi, bi, Wj, bj, Wfc, bfc,
        ws + OFF_ST3, bg3, bb3, a3, out);
}

// Round 5
// 261.038 us; speedup vs baseline: 6.8774x; 1.0585x over previous
//
#include <hip/hip_runtime.h>
#include <math.h>

#define NN 4096
#define NE 16384
#define NG 64

// ---- ws layout (float offsets) ----
#define OFF_DEG   0         // 4096
#define OFF_H1    4096      // 4096*32
#define OFF_H2    135168    // 4096*64
#define OFF_H3    397312    // 4096*128
#define OFF_ST1   921600    // 64
#define OFF_ST2   921664    // 128
#define OFF_ST3   921792    // 256
#define OFF_POOL  922048    // 64*128
#define OFF_WC1   930240    // 16*288  = 4608
#define OFF_WC2   934848    // 32*576  = 18432
#define OFF_WC3   953280    // 64*1152 = 73728
#define OFF_Y     1027008   // 4096*1152 = 4718592 (reused across layers)
#define ZERO_FLOATS 930240  // zero deg/h/stats/pool only

// ---------------- prep: Wcat build (We + be as 9th filter) + degree ----------------
// Wcat[i*(9*COUT) + f*COUT + o] = f<8 ? We[f*CIN*COUT + o*CIN + i] : be[o*CIN + i]
__device__ __forceinline__ void tr_wcat(const float* We, const float* be,
                                        float* Wcat, int CIN, int COUT, int t) {
    int nine = 9 * COUT;
    int i = t / nine; int r = t - i * nine;
    int f = r / COUT; int o = r - f * COUT;
    Wcat[t] = (f < 8) ? We[f * CIN * COUT + o * CIN + i] : be[o * CIN + i];
}

__global__ __launch_bounds__(256) void k_prep(
    const float* __restrict__ We1, const float* __restrict__ be1,
    const float* __restrict__ We2, const float* __restrict__ be2,
    const float* __restrict__ We3, const float* __restrict__ be3,
    const int* __restrict__ ei, float* __restrict__ ws)
{
    int t = blockIdx.x * 256 + threadIdx.x;
    if (t < 4608)  { tr_wcat(We1, be1, ws + OFF_WC1, 16, 32, t); return; }
    t -= 4608;
    if (t < 18432) { tr_wcat(We2, be2, ws + OFF_WC2, 32, 64, t); return; }
    t -= 18432;
    if (t < 73728) { tr_wcat(We3, be3, ws + OFF_WC3, 64, 128, t); return; }
    t -= 73728;
    if (t < NE)    { atomicAdd(&ws[OFF_DEG + ei[t]], 1.0f); }
}

// ---------------- proj GEMM: Y[n,col] = norm[n] * sum_i bnp(A[n,i]) * B[i,col] ----------------
// BM=64, BN=64, 256 threads, 4x4 per thread, K fully staged in LDS.
// BN=true: apply batchnorm(st/g/b) + PReLU(a) to A elements on load.
template<int K, bool BN>
__global__ __launch_bounds__(256) void k_proj(
    const float* __restrict__ A, const float* __restrict__ Bm,
    const float* __restrict__ deg, float* __restrict__ Y, int Ncols,
    const float* __restrict__ st, const float* __restrict__ g,
    const float* __restrict__ b, const float* __restrict__ a)
{
    __shared__ float sA[K][68];
    __shared__ float sB[K][68];
    __shared__ float sS[K];
    __shared__ float sT[K];
    const int tid = threadIdx.x;
    const int m0 = blockIdx.x * 64;
    const int n0 = blockIdx.y * 64;

    float al = 0.f;
    if constexpr (BN) {
        if (tid < K) {
            float mean = st[tid] * (1.f / NN);
            float var  = st[K + tid] * (1.f / NN) - mean * mean;
            var = fmaxf(var, 0.f);
            float s = rsqrtf(var + 1e-5f) * g[tid];
            sS[tid] = s;
            sT[tid] = b[tid] - mean * s;
        }
        al = a[0];
        __syncthreads();
    }

    for (int t = tid; t < 64 * K; t += 256) {
        int m = t / K, i = t - m * K;
        float v = A[(m0 + m) * K + i];
        if constexpr (BN) {
            v = fmaf(v, sS[i], sT[i]);
            v = v >= 0.f ? v : al * v;
        }
        sA[i][m] = v;
    }
    for (int t = tid; t < 64 * K; t += 256) {
        int i = t >> 6, n = t & 63;
        int col = n0 + n;
        sB[i][n] = (col < Ncols) ? Bm[i * Ncols + col] : 0.f;
    }
    __syncthreads();

    const int tn = tid & 15, tm = tid >> 4;
    float acc[4][4] = {{0.f}};
#pragma unroll 8
    for (int i = 0; i < K; ++i) {
        float4 av = *(const float4*)&sA[i][tm * 4];
        float4 bv = *(const float4*)&sB[i][tn * 4];
        acc[0][0] += av.x * bv.x; acc[0][1] += av.x * bv.y; acc[0][2] += av.x * bv.z; acc[0][3] += av.x * bv.w;
        acc[1][0] += av.y * bv.x; acc[1][1] += av.y * bv.y; acc[1][2] += av.y * bv.z; acc[1][3] += av.y * bv.w;
        acc[2][0] += av.z * bv.x; acc[2][1] += av.z * bv.y; acc[2][2] += av.z * bv.z; acc[2][3] += av.z * bv.w;
        acc[3][0] += av.w * bv.x; acc[3][1] += av.w * bv.y; acc[3][2] += av.w * bv.z; acc[3][3] += av.w * bv.w;
    }

#pragma unroll
    for (int mm = 0; mm < 4; ++mm) {
        int m = m0 + tm * 4 + mm;
        float d = deg[m];
        float nrm = d > 0.f ? 1.f / d : 0.f;
#pragma unroll
        for (int nn = 0; nn < 4; ++nn) {
            int col = n0 + tn * 4 + nn;
            if (col < Ncols) Y[(size_t)m * Ncols + col] = acc[mm][nn] * nrm;
        }
    }
}

// ---------------- per-edge gather: h[dst,o] += sum_f ea'[e,f] * Y[src, f*COUT+o] ----------------
// round-0 proven version: one scalar atomic per thread, fully parallel.
template<int COUT>
__global__ __launch_bounds__(256) void k_egather(
    const float* __restrict__ Y, const float* __restrict__ eattr,
    const int* __restrict__ ei, float* __restrict__ h)
{
    int idx = blockIdx.x * 256 + threadIdx.x;
    int e = idx / COUT;
    int o = idx - e * COUT;
    int src = ei[e], dst = ei[NE + e];
    const float* y = Y + (size_t)src * (9 * COUT);
    const float* ea = eattr + e * 8;
    float acc = y[8 * COUT + o];      // be-term, ea' = 1
#pragma unroll
    for (int f = 0; f < 8; ++f) acc += ea[f] * y[f * COUT + o];
    atomicAdd(&h[dst * COUT + o], acc);
}

// ---------------- node: residual + bias, accumulate BN stats ----------------
// BN=true: xin is pre-BN h of previous layer -> apply bn(st_in/g/b)+PReLU(a) on load.
// NB=16 for all layers -> 256 blocks (full-chip).
template<int CIN, int COUT, int KN, bool BN>
__global__ __launch_bounds__(256) void k_node(
    const float* __restrict__ xin, const float* __restrict__ Wr,
    const float* __restrict__ br, const float* __restrict__ bias,
    float* __restrict__ h, float* __restrict__ st_out,
    const float* __restrict__ st_in, const float* __restrict__ g,
    const float* __restrict__ b, const float* __restrict__ a)
{
    constexpr int NL = 256 / COUT;
    constexpr int NB = NL * KN;
    constexpr int CINP = CIN | 1;
    __shared__ float sWr[CIN * COUT];
    __shared__ float sX[NB * CINP];
    __shared__ float sred[256];
    __shared__ float sS[CIN];
    __shared__ float sT[CIN];
    const int tid = threadIdx.x;
    const int nbase = blockIdx.x * NB;

    if constexpr (BN) {
        if (tid < CIN) {
            float mean = st_in[tid] * (1.f / NN);
            float var  = st_in[CIN + tid] * (1.f / NN) - mean * mean;
            var = fmaxf(var, 0.f);
            float s = rsqrtf(var + 1e-5f) * g[tid];
            sS[tid] = s;
            sT[tid] = b[tid] - mean * s;
        }
    }
    for (int t = tid; t < CIN * COUT; t += 256) sWr[t] = Wr[t];
    __syncthreads();
    float al = 0.f;
    if constexpr (BN) al = a[0];

    for (int t = tid; t < NB * CIN; t += 256) {
        int r = t / CIN, i = t - r * CIN;
        float v = xin[(nbase + r) * CIN + i];
        if constexpr (BN) {
            v = fmaf(v, sS[i], sT[i]);
            v = v >= 0.f ? v : al * v;
        }
        sX[r * CINP + i] = v;
    }
    __syncthreads();

    const int o = tid % COUT;
    const int nl = tid / COUT;
    const float addc = bias[o] + br[o];
    float sum = 0.f, sumsq = 0.f;
#pragma unroll
    for (int k = 0; k < KN; ++k) {
        int r = nl * KN + k;
        float acc = addc;
        for (int i = 0; i < CIN; ++i)
            acc += sX[r * CINP + i] * sWr[i * COUT + o];
        int gi = (nbase + r) * COUT + o;
        float hv = h[gi] + acc;
        h[gi] = hv;
        sum += hv; sumsq += hv * hv;
    }
    sred[tid] = sum;
    __syncthreads();
    if (tid < COUT) {
        float s = 0.f;
        for (int q = 0; q < NL; ++q) s += sred[q * COUT + tid];
        atomicAdd(&st_out[tid], s);
    }
    __syncthreads();
    sred[tid] = sumsq;
    __syncthreads();
    if (tid < COUT) {
        float s = 0.f;
        for (int q = 0; q < NL; ++q) s += sred[q * COUT + tid];
        atomicAdd(&st_out[COUT + tid], s);
    }
}

// ---------------- pool: BN3+PReLU3 on load, gated attention, run-aggregated atomics ----------------
// 256 blocks x 16 nodes. batch sorted -> per-thread 8 consecutive nodes span few graphs;
// aggregate runs in registers, one atomic per run.
__global__ __launch_bounds__(256) void k_pool(
    const float* __restrict__ h3, const int* __restrict__ batch,
    const float* __restrict__ Wi, const float* __restrict__ bi,
    const float* __restrict__ Wj, const float* __restrict__ bj,
    float* __restrict__ pooled,
    const float* __restrict__ st, const float* __restrict__ g,
    const float* __restrict__ b, const float* __restrict__ a)
{
    constexpr int KN = 8, NB = 16;
    __shared__ float sH[NB * 128];
    __shared__ int sB[NB];
    __shared__ float sS[128];
    __shared__ float sT[128];
    const int tid = threadIdx.x;
    const int nbase = blockIdx.x * NB;

    if (tid < 128) {
        float mean = st[tid] * (1.f / NN);
        float var  = st[128 + tid] * (1.f / NN) - mean * mean;
        var = fmaxf(var, 0.f);
        float s = rsqrtf(var + 1e-5f) * g[tid];
        sS[tid] = s;
        sT[tid] = b[tid] - mean * s;
    }
    if (tid < NB) sB[tid] = batch[nbase + tid];
    __syncthreads();
    const float al = a[0];

    for (int t = tid; t < NB * 128; t += 256) {
        int c = t & 127;
        float v = h3[nbase * 128 + t];
        v = fmaf(v, sS[c], sT[c]);
        v = v >= 0.f ? v : al * v;
        sH[t] = v;
    }
    __syncthreads();

    const int o = tid & 127, nl = tid >> 7;
    float gacc[KN], facc[KN];
#pragma unroll
    for (int k = 0; k < KN; ++k) { gacc[k] = 0.f; facc[k] = 0.f; }
    for (int i = 0; i < 128; ++i) {
        float wi = Wi[i * 128 + o], wj = Wj[i * 128 + o];
#pragma unroll
        for (int k = 0; k < KN; ++k) {
            float hv = sH[(nl * KN + k) * 128 + i];
            gacc[k] += hv * wi;
            facc[k] += hv * wj;
        }
    }
    float bio = bi[o], bjo = bj[o];
    float psum = 0.f;
    int curg = sB[nl * KN];
#pragma unroll
    for (int k = 0; k < KN; ++k) {
        int r = nl * KN + k;
        int bg = sB[r];
        if (bg != curg) {
            atomicAdd(&pooled[curg * 128 + o], psum);
            psum = 0.f; curg = bg;
        }
        float gate = 1.f / (1.f + expf(-(gacc[k] + bio)));
        float feat = tanhf(facc[k] + bjo);
        psum += gate * feat;
    }
    atomicAdd(&pooled[curg * 128 + o], psum);
}

// ---------------- final: tanh(pooled) @ Wfc + bfc, split halves ----------------
__global__ __launch_bounds__(256) void k_final(
    const float* __restrict__ pooled, const float* __restrict__ Wfc,
    const float* __restrict__ bfc, float* __restrict__ out)
{
    __shared__ float sP[128];
    const int g = blockIdx.x, c = threadIdx.x;
    if (c < 128) sP[c] = tanhf(pooled[g * 128 + c]);
    __syncthreads();
    float z = bfc[c];
    for (int i = 0; i < 128; ++i) z += sP[i] * Wfc[i * 256 + c];
    int oidx = (c < 128) ? (g * 128 + c) : (NG * 128 + g * 128 + (c - 128));
    out[oidx] = z;
}

extern "C" void kernel_launch(void* const* d_in, const int* in_sizes, int n_in,
                              void* d_out, int out_size, void* d_ws, size_t ws_size,
                              hipStream_t stream)
{
    (void)in_sizes; (void)n_in; (void)out_size; (void)ws_size;
    const float* x     = (const float*)d_in[0];
    const float* eattr = (const float*)d_in[1];
    const int*   ei    = (const int*)d_in[2];
    const int*   batch = (const int*)d_in[3];
    const float* We1 = (const float*)d_in[4];
    const float* be1 = (const float*)d_in[5];
    const float* bias1 = (const float*)d_in[6];
    const float* Wr1 = (const float*)d_in[7];
    const float* br1 = (const float*)d_in[8];
    const float* bg1 = (const float*)d_in[9];
    const float* bb1 = (const float*)d_in[10];
    const float* a1  = (const float*)d_in[11];
    const float* We2 = (const float*)d_in[12];
    const float* be2 = (const float*)d_in[13];
    const float* bias2 = (const float*)d_in[14];
    const float* Wr2 = (const float*)d_in[15];
    const float* br2 = (const float*)d_in[16];
    const float* bg2 = (const float*)d_in[17];
    const float* bb2 = (const float*)d_in[18];
    const float* a2  = (const float*)d_in[19];
    const float* We3 = (const float*)d_in[20];
    const float* be3 = (const float*)d_in[21];
    const float* bias3 = (const float*)d_in[22];
    const float* Wr3 = (const float*)d_in[23];
    const float* br3 = (const float*)d_in[24];
    const float* bg3 = (const float*)d_in[25];
    const float* bb3 = (const float*)d_in[26];
    const float* a3  = (const float*)d_in[27];
    const float* Wi  = (const float*)d_in[28];
    const float* bi  = (const float*)d_in[29];
    const float* Wj  = (const float*)d_in[30];
    const float* bj  = (const float*)d_in[31];
    const float* Wfc = (const float*)d_in[32];
    const float* bfc = (const float*)d_in[33];
    float* ws  = (float*)d_ws;
    float* out = (float*)d_out;

    hipMemsetAsync(d_ws, 0, (size_t)ZERO_FLOATS * sizeof(float), stream);
    k_prep<<<442, 256, 0, stream>>>(We1, be1, We2, be2, We3, be3, ei, ws);

    // layer 1: cin=16, cout=32, Ncols=288 (no BN on x)
    k_proj<16, false><<<dim3(64, 5), 256, 0, stream>>>(
        x, ws + OFF_WC1, ws + OFF_DEG, ws + OFF_Y, 288,
        nullptr, nullptr, nullptr, nullptr);
    k_egather<32><<<NE * 32 / 256, 256, 0, stream>>>(ws + OFF_Y, eattr, ei, ws + OFF_H1);
    k_node<16, 32, 2, false><<<NN / 16, 256, 0, stream>>>(
        x, Wr1, br1, bias1, ws + OFF_H1, ws + OFF_ST1,
        nullptr, nullptr, nullptr, nullptr);

    // layer 2: cin=32, cout=64, Ncols=576 (BN1 folded into loads of h1)
    k_proj<32, true><<<dim3(64, 9), 256, 0, stream>>>(
        ws + OFF_H1, ws + OFF_WC2, ws + OFF_DEG, ws + OFF_Y, 576,
        ws + OFF_ST1, bg1, bb1, a1);
    k_egather<64><<<NE * 64 / 256, 256, 0, stream>>>(ws + OFF_Y, eattr, ei, ws + OFF_H2);
    k_node<32, 64, 4, true><<<NN / 16, 256, 0, stream>>>(
        ws + OFF_H1, Wr2, br2, bias2, ws + OFF_H2, ws + OFF_ST2,
        ws + OFF_ST1, bg1, bb1, a1);

    // layer 3: cin=64, cout=128, Ncols=1152 (BN2 folded)
    k_proj<64, true><<<dim3(64, 18), 256, 0, stream>>>(
        ws + OFF_H2, ws + OFF_WC3, ws + OFF_DEG, ws + OFF_Y, 1152,
        ws + OFF_ST2, bg2, bb2, a2);
    k_egather<128><<<NE * 128 / 256, 256, 0, stream>>>(ws + OFF_Y, eattr, ei, ws + OFF_H3);
    k_node<64, 128, 8, true><<<NN / 16, 256, 0, stream>>>(
        ws + OFF_H2, Wr3, br3, bias3, ws + OFF_H3, ws + OFF_ST3,
        ws + OFF_ST2, bg2, bb2, a2);

    // pooling (BN3 folded, run-aggregated atomics) + head
    k_pool<<<NN / 16, 256, 0, stream>>>(ws + OFF_H3, batch, Wi, bi, Wj, bj, ws + OFF_POOL,
                                        ws + OFF_ST3, bg3, bb3, a3);
    k_final<<<NG, 256, 0, stream>>>(ws + OFF_POOL, Wfc, bfc, out);
}

// Round 6
// 241.584 us; speedup vs baseline: 7.4312x; 1.0805x over previous
//
#include <hip/hip_runtime.h>
#include <math.h>

#define NN 4096
#define NE 16384
#define NG 64

// ---- ws layout (float offsets); zero region first (51KB memset) ----
#define OFF_DEG   0         // 4096
#define OFF_ST1   4096      // 64
#define OFF_ST2   4160      // 128
#define OFF_ST3   4288      // 256
#define OFF_POOL  4544      // 64*128 = 8192
#define ZERO_FLOATS 12736
#define OFF_H1    12736     // 4096*32
#define OFF_H2    143808    // 4096*64
#define OFF_H3    405952    // 4096*128
#define OFF_Y     930240    // 4096*1152 max (reused across layers)

// ---------------- proj: Y[n,col]=sum_i bnp(A[n,i])*Bcat[i,col]; resid cols -> h-init ----------------
// Bcat built on the fly from We/be/Wr (no materialization):
//   col = f*COUT + o;  f<8 -> We[f*K*COUT + o*K + i];  f==8 -> be[o*K+i];  f==9 -> Wr[i*COUT+o]
// cols < 9*COUT -> Y (unnormalized; norm applied in egather)
// cols >= 9*COUT -> h[m*COUT+o] = acc + bias[o] + br[o]   (residual init, written once)
// DEG=true: trailing 64 blocks count src out-degree (independent work, merged launch).
template<int K, int COUT, bool BN, bool DEG>
__global__ __launch_bounds__(256) void k_proj(
    const float* __restrict__ A,
    const float* __restrict__ We, const float* __restrict__ be,
    const float* __restrict__ Wr, const float* __restrict__ bias,
    const float* __restrict__ br,
    const int* __restrict__ ei, float* __restrict__ deg,
    float* __restrict__ Y, float* __restrict__ h,
    const float* __restrict__ st, const float* __restrict__ g,
    const float* __restrict__ b, const float* __restrict__ a)
{
    constexpr int NCOL = 10 * COUT;
    constexpr int NY = NCOL / 64;       // exact: 5 / 10 / 20
    constexpr int NC9 = 9 * COUT;
    constexpr int L2C = (COUT == 32) ? 5 : (COUT == 64) ? 6 : 7;

    const int tid = threadIdx.x;
    const int bid = blockIdx.x;

    if constexpr (DEG) {
        if (bid >= 64 * NY) {
            int e = (bid - 64 * NY) * 256 + tid;
            if (e < NE) atomicAdd(&deg[ei[e]], 1.0f);
            return;
        }
    }

    __shared__ float sA[K][68];
    __shared__ float sB[K][68];
    __shared__ float sS[K];
    __shared__ float sT[K];
    const int m0 = (bid & 63) * 64;
    const int n0 = (bid >> 6) * 64;

    float al = 0.f;
    if constexpr (BN) {
        if (tid < K) {
            float mean = st[tid] * (1.f / NN);
            float var  = st[K + tid] * (1.f / NN) - mean * mean;
            var = fmaxf(var, 0.f);
            float s = rsqrtf(var + 1e-5f) * g[tid];
            sS[tid] = s;
            sT[tid] = b[tid] - mean * s;
        }
        al = a[0];
        __syncthreads();
    }

    for (int t = tid; t < 64 * K; t += 256) {
        int m = t / K, i = t - m * K;
        float v = A[(m0 + m) * K + i];
        if constexpr (BN) {
            v = fmaf(v, sS[i], sT[i]);
            v = v >= 0.f ? v : al * v;
        }
        sA[i][m] = v;
    }
    for (int t = tid; t < 64 * K; t += 256) {
        int i = t >> 6, n = t & 63;
        int col = n0 + n;
        int f = col >> L2C;
        int o = col & (COUT - 1);
        float v;
        if (f < 8)       v = We[f * K * COUT + o * K + i];
        else if (f == 8) v = be[o * K + i];
        else             v = Wr[i * COUT + o];
        sB[i][n] = v;
    }
    __syncthreads();

    const int tn = tid & 15, tm = tid >> 4;
    float acc[4][4] = {{0.f}};
#pragma unroll 8
    for (int i = 0; i < K; ++i) {
        float4 av = *(const float4*)&sA[i][tm * 4];
        float4 bv = *(const float4*)&sB[i][tn * 4];
        acc[0][0] += av.x * bv.x; acc[0][1] += av.x * bv.y; acc[0][2] += av.x * bv.z; acc[0][3] += av.x * bv.w;
        acc[1][0] += av.y * bv.x; acc[1][1] += av.y * bv.y; acc[1][2] += av.y * bv.z; acc[1][3] += av.y * bv.w;
        acc[2][0] += av.z * bv.x; acc[2][1] += av.z * bv.y; acc[2][2] += av.z * bv.z; acc[2][3] += av.z * bv.w;
        acc[3][0] += av.w * bv.x; acc[3][1] += av.w * bv.y; acc[3][2] += av.w * bv.z; acc[3][3] += av.w * bv.w;
    }

#pragma unroll
    for (int mm = 0; mm < 4; ++mm) {
        int m = m0 + tm * 4 + mm;
#pragma unroll
        for (int nn = 0; nn < 4; ++nn) {
            int col = n0 + tn * 4 + nn;
            if (col < NC9) {
                Y[(size_t)m * NC9 + col] = acc[mm][nn];
            } else {
                int o = col - NC9;
                h[m * COUT + o] = acc[mm][nn] + bias[o] + br[o];
            }
        }
    }
}

// ---------------- egather: h[dst,o] += (1/deg[src]) * (sum_f ea[f]*Y[src,f*COUT+o] + Y[src,8*COUT+o]) ----------------
template<int COUT>
__global__ __launch_bounds__(256) void k_egather(
    const float* __restrict__ Y, const float* __restrict__ eattr,
    const int* __restrict__ ei, const float* __restrict__ deg,
    float* __restrict__ h)
{
    int idx = blockIdx.x * 256 + threadIdx.x;
    int e = idx / COUT;
    int o = idx - e * COUT;
    int src = ei[e], dst = ei[NE + e];
    float d = deg[src];
    float nrm = d > 0.f ? 1.f / d : 0.f;
    const float* y = Y + (size_t)src * (9 * COUT);
    const float* ea = eattr + e * 8;
    float acc = y[8 * COUT + o];      // be-term, ea' = 1
#pragma unroll
    for (int f = 0; f < 8; ++f) acc += ea[f] * y[f * COUT + o];
    atomicAdd(&h[dst * COUT + o], nrm * acc);
}

// ---------------- stats: per-channel sum/sumsq of h -> st ----------------
template<int COUT>
__global__ __launch_bounds__(256) void k_stats(
    const float* __restrict__ h, float* __restrict__ st)
{
    constexpr int NL = 256 / COUT;
    constexpr int KN = 16 / NL;
    __shared__ float sred[256];
    const int tid = threadIdx.x;
    const int nbase = blockIdx.x * 16;
    const int o = tid % COUT;
    const int nl = tid / COUT;

    float sum = 0.f, sumsq = 0.f;
#pragma unroll
    for (int k = 0; k < KN; ++k) {
        int r = nl * KN + k;
        float v = h[(nbase + r) * COUT + o];
        sum += v; sumsq += v * v;
    }
    sred[tid] = sum;
    __syncthreads();
    if (tid < COUT) {
        float s = 0.f;
        for (int q = 0; q < NL; ++q) s += sred[q * COUT + tid];
        atomicAdd(&st[tid], s);
    }
    __syncthreads();
    sred[tid] = sumsq;
    __syncthreads();
    if (tid < COUT) {
        float s = 0.f;
        for (int q = 0; q < NL; ++q) s += sred[q * COUT + tid];
        atomicAdd(&st[COUT + tid], s);
    }
}

// ---------------- pool: BN3+PReLU3 on load, gated attention, run-aggregated atomics ----------------
__global__ __launch_bounds__(256) void k_pool(
    const float* __restrict__ h3, const int* __restrict__ batch,
    const float* __restrict__ Wi, const float* __restrict__ bi,
    const float* __restrict__ Wj, const float* __restrict__ bj,
    float* __restrict__ pooled,
    const float* __restrict__ st, const float* __restrict__ g,
    const float* __restrict__ b, const float* __restrict__ a)
{
    constexpr int KN = 8, NB = 16;
    __shared__ float sH[NB * 128];
    __shared__ int sB[NB];
    __shared__ float sS[128];
    __shared__ float sT[128];
    const int tid = threadIdx.x;
    const int nbase = blockIdx.x * NB;

    if (tid < 128) {
        float mean = st[tid] * (1.f / NN);
        float var  = st[128 + tid] * (1.f / NN) - mean * mean;
        var = fmaxf(var, 0.f);
        float s = rsqrtf(var + 1e-5f) * g[tid];
        sS[tid] = s;
        sT[tid] = b[tid] - mean * s;
    }
    if (tid < NB) sB[tid] = batch[nbase + tid];
    __syncthreads();
    const float al = a[0];

    for (int t = tid; t < NB * 128; t += 256) {
        int c = t & 127;
        float v = h3[nbase * 128 + t];
        v = fmaf(v, sS[c], sT[c]);
        v = v >= 0.f ? v : al * v;
        sH[t] = v;
    }
    __syncthreads();

    const int o = tid & 127, nl = tid >> 7;
    float gacc[KN], facc[KN];
#pragma unroll
    for (int k = 0; k < KN; ++k) { gacc[k] = 0.f; facc[k] = 0.f; }
    for (int i = 0; i < 128; ++i) {
        float wi = Wi[i * 128 + o], wj = Wj[i * 128 + o];
#pragma unroll
        for (int k = 0; k < KN; ++k) {
            float hv = sH[(nl * KN + k) * 128 + i];
            gacc[k] += hv * wi;
            facc[k] += hv * wj;
        }
    }
    float bio = bi[o], bjo = bj[o];
    float psum = 0.f;
    int curg = sB[nl * KN];
#pragma unroll
    for (int k = 0; k < KN; ++k) {
        int r = nl * KN + k;
        int bg = sB[r];
        if (bg != curg) {
            atomicAdd(&pooled[curg * 128 + o], psum);
            psum = 0.f; curg = bg;
        }
        float gate = 1.f / (1.f + expf(-(gacc[k] + bio)));
        float feat = tanhf(facc[k] + bjo);
        psum += gate * feat;
    }
    atomicAdd(&pooled[curg * 128 + o], psum);
}

// ---------------- final: tanh(pooled) @ Wfc + bfc, split halves ----------------
__global__ __launch_bounds__(256) void k_final(
    const float* __restrict__ pooled, const float* __restrict__ Wfc,
    const float* __restrict__ bfc, float* __restrict__ out)
{
    __shared__ float sP[128];
    const int g = blockIdx.x, c = threadIdx.x;
    if (c < 128) sP[c] = tanhf(pooled[g * 128 + c]);
    __syncthreads();
    float z = bfc[c];
    for (int i = 0; i < 128; ++i) z += sP[i] * Wfc[i * 256 + c];
    int oidx = (c < 128) ? (g * 128 + c) : (NG * 128 + g * 128 + (c - 128));
    out[oidx] = z;
}

extern "C" void kernel_launch(void* const* d_in, const int* in_sizes, int n_in,
                              void* d_out, int out_size, void* d_ws, size_t ws_size,
                              hipStream_t stream)
{
    (void)in_sizes; (void)n_in; (void)out_size; (void)ws_size;
    const float* x     = (const float*)d_in[0];
    const float* eattr = (const float*)d_in[1];
    const int*   ei    = (const int*)d_in[2];
    const int*   batch = (const int*)d_in[3];
    const float* We1 = (const float*)d_in[4];
    const float* be1 = (const float*)d_in[5];
    const float* bias1 = (const float*)d_in[6];
    const float* Wr1 = (const float*)d_in[7];
    const float* br1 = (const float*)d_in[8];
    const float* bg1 = (const float*)d_in[9];
    const float* bb1 = (const float*)d_in[10];
    const float* a1  = (const float*)d_in[11];
    const float* We2 = (const float*)d_in[12];
    const float* be2 = (const float*)d_in[13];
    const float* bias2 = (const float*)d_in[14];
    const float* Wr2 = (const float*)d_in[15];
    const float* br2 = (const float*)d_in[16];
    const float* bg2 = (const float*)d_in[17];
    const float* bb2 = (const float*)d_in[18];
    const float* a2  = (const float*)d_in[19];
    const float* We3 = (const float*)d_in[20];
    const float* be3 = (const float*)d_in[21];
    const float* bias3 = (const float*)d_in[22];
    const float* Wr3 = (const float*)d_in[23];
    const float* br3 = (const float*)d_in[24];
    const float* bg3 = (const float*)d_in[25];
    const float* bb3 = (const float*)d_in[26];
    const float* a3  = (const float*)d_in[27];
    const float* Wi  = (const float*)d_in[28];
    const float* bi  = (const float*)d_in[29];
    const float* Wj  = (const float*)d_in[30];
    const float* bj  = (const float*)d_in[31];
    const float* Wfc = (const float*)d_in[32];
    const float* bfc = (const float*)d_in[33];
    float* ws  = (float*)d_ws;
    float* out = (float*)d_out;

    hipMemsetAsync(d_ws, 0, (size_t)ZERO_FLOATS * sizeof(float), stream);

    // layer 1: K=16, COUT=32 (no BN on x); deg-count blocks merged into proj1 launch
    k_proj<16, 32, false, true><<<64 * 5 + 64, 256, 0, stream>>>(
        x, We1, be1, Wr1, bias1, br1, ei, ws + OFF_DEG,
        ws + OFF_Y, ws + OFF_H1, nullptr, nullptr, nullptr, nullptr);
    k_egather<32><<<NE * 32 / 256, 256, 0, stream>>>(
        ws + OFF_Y, eattr, ei, ws + OFF_DEG, ws + OFF_H1);
    k_stats<32><<<NN / 16, 256, 0, stream>>>(ws + OFF_H1, ws + OFF_ST1);

    // layer 2: K=32, COUT=64 (BN1 folded into A load)
    k_proj<32, 64, true, false><<<64 * 10, 256, 0, stream>>>(
        ws + OFF_H1, We2, be2, Wr2, bias2, br2, nullptr, nullptr,
        ws + OFF_Y, ws + OFF_H2, ws + OFF_ST1, bg1, bb1, a1);
    k_egather<64><<<NE * 64 / 256, 256, 0, stream>>>(
        ws + OFF_Y, eattr, ei, ws + OFF_DEG, ws + OFF_H2);
    k_stats<64><<<NN / 16, 256, 0, stream>>>(ws + OFF_H2, ws + OFF_ST2);

    // layer 3: K=64, COUT=128 (BN2 folded)
    k_proj<64, 128, true, false><<<64 * 20, 256, 0, stream>>>(
        ws + OFF_H2, We3, be3, Wr3, bias3, br3, nullptr, nullptr,
        ws + OFF_Y, ws + OFF_H3, ws + OFF_ST2, bg2, bb2, a2);
    k_egather<128><<<NE * 128 / 256, 256, 0, stream>>>(
        ws + OFF_Y, eattr, ei, ws + OFF_DEG, ws + OFF_H3);
    k_stats<128><<<NN / 16, 256, 0, stream>>>(ws + OFF_H3, ws + OFF_ST3);

    // pooling (BN3 folded, run-aggregated atomics) + head
    k_pool<<<NN / 16, 256, 0, stream>>>(ws + OFF_H3, batch, Wi, bi, Wj, bj, ws + OFF_POOL,
                                        ws + OFF_ST3, bg3, bb3, a3);
    k_final<<<NG, 256, 0, stream>>>(ws + OFF_POOL, Wfc, bfc, out);
}